// Round 11
// baseline (37.533 us; speedup 1.0000x reference)
//
#include <hip/hip_runtime.h>
#include <hip/hip_bf16.h>

// Guided attention loss, two-kernel (r10 body) + PROBE: k1 launched twice.
//   Round 11 is a measurement round: the second, redundant k1 dispatch
//   (writing a disjoint part region, never read) exposes warm-k1's marginal
//   cost as (dur - 22.25us). Functional path identical to r10.
//   guided(b,x,y) = 1 - exp(-(y/il - x/ol)^2 / (2*sigma^2)),  sigma=0.4
//   out[b]   = sum(guided*att over valid) / ol
//   out[B+b] = sum((guided*att)^2 over valid) / ol
// Shapes fixed: B=64, T_out=2048, T_in=512.

#define GA_B     64
#define GA_TOUT  2048
#define GA_TIN   512
#define ROWS_PER_WAVE   8
#define WAVES_PER_BLOCK 4
#define ROWS_PER_BLOCK  (ROWS_PER_WAVE * WAVES_PER_BLOCK)   // 32
#define BLOCK_THREADS   256
#define GRID_X          (GA_TOUT / ROWS_PER_BLOCK)           // 64
// KS = sqrt(3.125 * log2(e)):  2^(-(KS*z)^2) = exp(-z^2 * 3.125)
#define KS 2.1233046f

__global__ __launch_bounds__(BLOCK_THREADS)
void ga_partial_kernel(const float* __restrict__ att,
                       const int* __restrict__ ilens,
                       const int* __restrict__ olens,
                       float2* __restrict__ part) {
    const int b    = blockIdx.y;
    const int lane = threadIdx.x & 63;
    const int wave = threadIdx.x >> 6;
    const int waveRow = blockIdx.x * ROWS_PER_BLOCK + wave * ROWS_PER_WAVE;

    const int ol = olens[b];
    const int il = ilens[b];

    float l1 = 0.0f, l2 = 0.0f;

    if (waveRow < ol) {
        const int q = lane >> 4;                 // row within 4-row group
        const int l = lane & 15;                 // column sub-group
        const int full_w = il >> 6;              // fully-valid 64-col windows
        const int nw     = (il + 63) >> 6;       // total windows incl. boundary

        const float inv_il_s = KS / (float)il;
        const float inv_ol_s = KS / (float)ol;
        const float* __restrict__ bbase = att + (size_t)b * GA_TOUT * GA_TIN;

        int   row[2];
        float gx[2];
        #pragma unroll
        for (int g = 0; g < 2; ++g) {
            row[g] = waveRow + g * 4 + q;
            gx[g]  = (float)row[g] * inv_ol_s;
        }

        float ysb[4];
        #pragma unroll
        for (int j = 0; j < 4; ++j)
            ysb[j] = (float)((l << 2) + j) * inv_il_s;

        float mb[4];
        #pragma unroll
        for (int j = 0; j < 4; ++j) {
            const int col = (full_w << 6) + (l << 2) + j;
            mb[j] = (col < il) ? 1.0f : 0.0f;
        }

        float4 A[2][8];
        #pragma unroll
        for (int w = 0; w < 8; ++w) {
            #pragma unroll
            for (int g = 0; g < 2; ++g) {
                A[g][w] = make_float4(0.f, 0.f, 0.f, 0.f);
                if (w < nw && row[g] < ol) {
                    A[g][w] = ((const float4*)(bbase + (size_t)row[g] * GA_TIN))
                              [(w << 4) + l];
                }
            }
        }

        #pragma unroll
        for (int w = 0; w < 8; ++w) {
            if (w < full_w) {                       // wave-uniform: unmasked
                const float off = (float)(w << 6) * inv_il_s;
                #pragma unroll
                for (int g = 0; g < 2; ++g) {
                    const float  c = off - gx[g];
                    const float4 a = A[g][w];
                    #pragma unroll
                    for (int j = 0; j < 4; ++j) {
                        const float av = (j == 0) ? a.x : (j == 1) ? a.y
                                       : (j == 2) ? a.z : a.w;
                        const float wv = ysb[j] + c;
                        const float E  = exp2f(-wv * wv);
                        const float e  = av - av * E;
                        l1 += e;
                        l2 += e * e;
                    }
                }
            } else if (w < nw) {                    // boundary window: masked
                const float off = (float)(w << 6) * inv_il_s;
                #pragma unroll
                for (int g = 0; g < 2; ++g) {
                    const float  c = off - gx[g];
                    const float4 a = A[g][w];
                    #pragma unroll
                    for (int j = 0; j < 4; ++j) {
                        const float av = (j == 0) ? a.x : (j == 1) ? a.y
                                       : (j == 2) ? a.z : a.w;
                        const float wv = ysb[j] + c;
                        const float E  = exp2f(-wv * wv);
                        const float e  = (av - av * E) * mb[j];
                        l1 += e;
                        l2 += e * e;
                    }
                }
            }
        }
    }

    #pragma unroll
    for (int o = 32; o > 0; o >>= 1) {
        l1 += __shfl_down(l1, o, 64);
        l2 += __shfl_down(l2, o, 64);
    }
    __shared__ float s1[WAVES_PER_BLOCK];
    __shared__ float s2[WAVES_PER_BLOCK];
    if (lane == 0) { s1[wave] = l1; s2[wave] = l2; }
    __syncthreads();
    if (threadIdx.x == 0) {
        const float b1 = s1[0] + s1[1] + s1[2] + s1[3];
        const float b2 = s2[0] + s2[1] + s2[2] + s2[3];
        part[b * GRID_X + blockIdx.x] = make_float2(b1, b2);
    }
}

__global__ __launch_bounds__(64)
void ga_final_kernel(const float2* __restrict__ part,
                     const int* __restrict__ olens,
                     float* __restrict__ out) {
    const int b = blockIdx.x;
    const int t = threadIdx.x;
    const float2 p = part[b * GRID_X + t];   // exactly 64 chunks per batch
    float l1 = p.x, l2 = p.y;
    #pragma unroll
    for (int o = 32; o > 0; o >>= 1) {
        l1 += __shfl_down(l1, o, 64);
        l2 += __shfl_down(l2, o, 64);
    }
    if (t == 0) {
        const float d = (float)olens[b];
        out[b]        = l1 / d;
        out[GA_B + b] = l2 / d;
    }
}

extern "C" void kernel_launch(void* const* d_in, const int* in_sizes, int n_in,
                              void* d_out, int out_size, void* d_ws, size_t ws_size,
                              hipStream_t stream) {
    const float* att   = (const float*)d_in[0];
    const int*   ilens = (const int*)d_in[1];
    const int*   olens = (const int*)d_in[2];
    float*       out   = (float*)d_out;
    float2*      part0 = (float2*)d_ws;                        // 32 KB
    float2*      part1 = (float2*)((char*)d_ws + 64 * 1024);   // probe sink

    dim3 grid1(GRID_X, GA_B);
    // PROBE: identical k1 twice; second writes a never-read region.
    ga_partial_kernel<<<grid1, BLOCK_THREADS, 0, stream>>>(att, ilens, olens, part0);
    ga_partial_kernel<<<grid1, BLOCK_THREADS, 0, stream>>>(att, ilens, olens, part1);
    ga_final_kernel<<<GA_B, 64, 0, stream>>>(part0, olens, out);
}

// Round 12
// 25.789 us; speedup vs baseline: 1.4554x; 1.4554x over previous
//
#include <hip/hip_runtime.h>
#include <hip/hip_bf16.h>

// Guided attention loss, two-kernel (r10 body, r12 occupancy/traffic/balance).
//   guided(b,x,y) = 1 - exp(-(y/il - x/ol)^2 / (2*sigma^2)),  sigma=0.4
//   out[b]   = sum(guided*att over valid) / ol
//   out[B+b] = sum((guided*att)^2 over valid) / ol
// Shapes fixed: B=64, T_out=2048, T_in=512.
//
// Round 12 vs r10:
//  - two-pass windows: A[2][4] regs reused across halves (VGPR ~96 -> ~68,
//    ~5 -> ~7-8 waves/SIMD; r11 probe showed k1=15.3us is ~60% un-hidden
//    latency at 5 waves/SIMD). Pass 2 skipped wave-uniformly when nw<=4.
//  - float4-exact load predicate (w*16+l < nv): ~10% fewer issued bytes.
//  - grid axes swapped (x=batch fastest): dispatch rounds mix batches ->
//    balanced rounds, no heavy-batch tail.

#define GA_B     64
#define GA_TOUT  2048
#define GA_TIN   512
#define ROWS_PER_WAVE   8
#define WAVES_PER_BLOCK 4
#define ROWS_PER_BLOCK  (ROWS_PER_WAVE * WAVES_PER_BLOCK)   // 32
#define BLOCK_THREADS   256
#define GRID_X          (GA_TOUT / ROWS_PER_BLOCK)           // 64 row-chunks
// KS = sqrt(3.125 * log2(e)):  2^(-(KS*z)^2) = exp(-z^2 * 3.125)
#define KS 2.1233046f

__global__ __launch_bounds__(BLOCK_THREADS)
void ga_partial_kernel(const float* __restrict__ att,
                       const int* __restrict__ ilens,
                       const int* __restrict__ olens,
                       float2* __restrict__ part) {
    const int b    = blockIdx.x;                 // batch (fast axis)
    const int rc   = blockIdx.y;                 // row chunk
    const int lane = threadIdx.x & 63;
    const int wave = threadIdx.x >> 6;
    const int waveRow = rc * ROWS_PER_BLOCK + wave * ROWS_PER_WAVE;

    const int ol = olens[b];
    const int il = ilens[b];

    float l1 = 0.0f, l2 = 0.0f;

    if (waveRow < ol) {
        const int q = lane >> 4;                 // row within 4-row group
        const int l = lane & 15;                 // column sub-group
        const int nv     = (il + 3) >> 2;        // valid float4 chunks (<=128)
        const int full_w = il >> 6;              // fully-valid 64-col windows
        const int nw     = (il + 63) >> 6;       // total windows incl. boundary

        const float inv_il_s = KS / (float)il;
        const float inv_ol_s = KS / (float)ol;
        const float* __restrict__ bbase = att + (size_t)b * GA_TOUT * GA_TIN;

        int   row[2];
        float gx[2];
        const float4* __restrict__ rowp[2];
        #pragma unroll
        for (int g = 0; g < 2; ++g) {
            row[g]  = waveRow + g * 4 + q;
            gx[g]   = (float)row[g] * inv_ol_s;
            rowp[g] = (const float4*)(bbase + (size_t)row[g] * GA_TIN);
        }

        float ysb[4];
        #pragma unroll
        for (int j = 0; j < 4; ++j)
            ysb[j] = (float)((l << 2) + j) * inv_il_s;

        // boundary-window (index full_w) column masks
        float mb[4];
        #pragma unroll
        for (int j = 0; j < 4; ++j) {
            const int col = (full_w << 6) + (l << 2) + j;
            mb[j] = (col < il) ? 1.0f : 0.0f;
        }

        #pragma unroll
        for (int half = 0; half < 2; ++half) {
            const int wbase = half << 2;
            if (wbase < nw) {                     // wave-uniform half skip
                // ---- load 4 windows (float4-exact predicate) ----
                float4 A[2][4];
                #pragma unroll
                for (int wi = 0; wi < 4; ++wi) {
                    const int chunk = ((wbase + wi) << 4) + l;
                    #pragma unroll
                    for (int g = 0; g < 2; ++g) {
                        A[g][wi] = make_float4(0.f, 0.f, 0.f, 0.f);
                        if (chunk < nv && row[g] < ol)
                            A[g][wi] = rowp[g][chunk];
                    }
                }
                // ---- compute 4 windows ----
                #pragma unroll
                for (int wi = 0; wi < 4; ++wi) {
                    const int w = wbase + wi;
                    if (w < full_w) {             // wave-uniform: unmasked
                        const float off = (float)(w << 6) * inv_il_s;
                        #pragma unroll
                        for (int g = 0; g < 2; ++g) {
                            const float  c = off - gx[g];
                            const float4 a = A[g][wi];
                            #pragma unroll
                            for (int j = 0; j < 4; ++j) {
                                const float av = (j == 0) ? a.x : (j == 1) ? a.y
                                               : (j == 2) ? a.z : a.w;
                                const float wv = ysb[j] + c;
                                const float E  = exp2f(-wv * wv);
                                const float e  = av - av * E;
                                l1 += e;
                                l2 += e * e;
                            }
                        }
                    } else if (w < nw) {          // boundary window: masked
                        const float off = (float)(w << 6) * inv_il_s;
                        #pragma unroll
                        for (int g = 0; g < 2; ++g) {
                            const float  c = off - gx[g];
                            const float4 a = A[g][wi];
                            #pragma unroll
                            for (int j = 0; j < 4; ++j) {
                                const float av = (j == 0) ? a.x : (j == 1) ? a.y
                                               : (j == 2) ? a.z : a.w;
                                const float wv = ysb[j] + c;
                                const float E  = exp2f(-wv * wv);
                                const float e  = (av - av * E) * mb[j];
                                l1 += e;
                                l2 += e * e;
                            }
                        }
                    }
                }
            }
        }
    }

    // ---- block reduce (4 waves); ALWAYS write so k2 may read every chunk ----
    #pragma unroll
    for (int o = 32; o > 0; o >>= 1) {
        l1 += __shfl_down(l1, o, 64);
        l2 += __shfl_down(l2, o, 64);
    }
    __shared__ float s1[WAVES_PER_BLOCK];
    __shared__ float s2[WAVES_PER_BLOCK];
    if (lane == 0) { s1[wave] = l1; s2[wave] = l2; }
    __syncthreads();
    if (threadIdx.x == 0) {
        const float b1 = s1[0] + s1[1] + s1[2] + s1[3];
        const float b2 = s2[0] + s2[1] + s2[2] + s2[3];
        part[b * GRID_X + rc] = make_float2(b1, b2);
    }
}

__global__ __launch_bounds__(64)
void ga_final_kernel(const float2* __restrict__ part,
                     const int* __restrict__ olens,
                     float* __restrict__ out) {
    const int b = blockIdx.x;
    const int t = threadIdx.x;
    const float2 p = part[b * GRID_X + t];   // exactly 64 chunks per batch
    float l1 = p.x, l2 = p.y;
    #pragma unroll
    for (int o = 32; o > 0; o >>= 1) {
        l1 += __shfl_down(l1, o, 64);
        l2 += __shfl_down(l2, o, 64);
    }
    if (t == 0) {
        const float d = (float)olens[b];
        out[b]        = l1 / d;
        out[GA_B + b] = l2 / d;
    }
}

extern "C" void kernel_launch(void* const* d_in, const int* in_sizes, int n_in,
                              void* d_out, int out_size, void* d_ws, size_t ws_size,
                              hipStream_t stream) {
    const float* att   = (const float*)d_in[0];
    const int*   ilens = (const int*)d_in[1];
    const int*   olens = (const int*)d_in[2];
    float*       out   = (float*)d_out;
    float2*      part  = (float2*)d_ws;   // 64 * 64 * 8 B = 32 KB

    dim3 grid1(GA_B, GRID_X);             // batch fastest -> balanced rounds
    ga_partial_kernel<<<grid1, BLOCK_THREADS, 0, stream>>>(att, ilens, olens, part);
    ga_final_kernel<<<GA_B, 64, 0, stream>>>(part, olens, out);
}

// Round 13
// 22.213 us; speedup vs baseline: 1.6897x; 1.1610x over previous
//
#include <hip/hip_runtime.h>
#include <hip/hip_bf16.h>

// Guided attention loss, two-kernel. r13 = r10 body with 1-wave blocks.
//   guided(b,x,y) = 1 - exp(-(y/il - x/ol)^2 / (2*sigma^2)),  sigma=0.4
//   out[b]   = sum(guided*att over valid) / ol
//   out[B+b] = sum((guided*att)^2 over valid) / ol
// Shapes fixed: B=64, T_out=2048, T_in=512.
//
// Round 13 (ONE change vs r10): 64-thread blocks (1 wave). 16384 blocks,
// independent retirement -> staggered starts break the convoy (r10's 4-wave
// blocks stall in lockstep: setup -> ~900cy first-load wait -> compute ->
// barrier). No __syncthreads / LDS reduce; dead blocks exit instantly.
// k2 reads only live chunks (c < ceil(ol/8)) so stale partials are never read.
// r12 lesson: bundled changes unattributable; two-pass load split regressed.

#define GA_B     64
#define GA_TOUT  2048
#define GA_TIN   512
#define ROWS_PER_WAVE   8
#define NCHUNK          (GA_TOUT / ROWS_PER_WAVE)    // 256 chunks per batch
// KS = sqrt(3.125 * log2(e)):  2^(-(KS*z)^2) = exp(-z^2 * 3.125)
#define KS 2.1233046f

__global__ __launch_bounds__(64)
void ga_partial_kernel(const float* __restrict__ att,
                       const int* __restrict__ ilens,
                       const int* __restrict__ olens,
                       float2* __restrict__ part) {
    const int b       = blockIdx.y;
    const int waveRow = blockIdx.x * ROWS_PER_WAVE;
    const int ol      = olens[b];
    if (waveRow >= ol) return;                   // dead block: k2 won't read it

    const int lane = threadIdx.x;
    const int il   = ilens[b];

    const int q = lane >> 4;                     // row within 4-row group
    const int l = lane & 15;                     // column sub-group
    const int full_w = il >> 6;                  // fully-valid 64-col windows
    const int nw     = (il + 63) >> 6;           // total windows incl. boundary

    const float inv_il_s = KS / (float)il;
    const float inv_ol_s = KS / (float)ol;
    const float* __restrict__ bbase = att + (size_t)b * GA_TOUT * GA_TIN;

    int   row[2];
    float gx[2];
    #pragma unroll
    for (int g = 0; g < 2; ++g) {
        row[g] = waveRow + g * 4 + q;
        gx[g]  = (float)row[g] * inv_ol_s;
    }

    float ysb[4];
    #pragma unroll
    for (int j = 0; j < 4; ++j)
        ysb[j] = (float)((l << 2) + j) * inv_il_s;

    // boundary-window (index full_w) column masks
    float mb[4];
    #pragma unroll
    for (int j = 0; j < 4; ++j) {
        const int col = (full_w << 6) + (l << 2) + j;
        mb[j] = (col < il) ? 1.0f : 0.0f;
    }

    // ---- loads: up to 16 float4 issued before compute ----
    float4 A[2][8];
    #pragma unroll
    for (int w = 0; w < 8; ++w) {
        #pragma unroll
        for (int g = 0; g < 2; ++g) {
            A[g][w] = make_float4(0.f, 0.f, 0.f, 0.f);
            if (w < nw && row[g] < ol) {
                A[g][w] = ((const float4*)(bbase + (size_t)row[g] * GA_TIN))
                          [(w << 4) + l];
            }
        }
    }

    float l1 = 0.0f, l2 = 0.0f;

    // ---- compute: full windows unmasked, boundary window masked ----
    #pragma unroll
    for (int w = 0; w < 8; ++w) {
        if (w < full_w) {                        // wave-uniform: unmasked
            const float off = (float)(w << 6) * inv_il_s;
            #pragma unroll
            for (int g = 0; g < 2; ++g) {
                const float  c = off - gx[g];
                const float4 a = A[g][w];
                #pragma unroll
                for (int j = 0; j < 4; ++j) {
                    const float av = (j == 0) ? a.x : (j == 1) ? a.y
                                   : (j == 2) ? a.z : a.w;
                    const float wv = ysb[j] + c;
                    const float E  = exp2f(-wv * wv);
                    const float e  = av - av * E;
                    l1 += e;
                    l2 += e * e;
                }
            }
        } else if (w < nw) {                     // boundary window: masked
            const float off = (float)(w << 6) * inv_il_s;
            #pragma unroll
            for (int g = 0; g < 2; ++g) {
                const float  c = off - gx[g];
                const float4 a = A[g][w];
                #pragma unroll
                for (int j = 0; j < 4; ++j) {
                    const float av = (j == 0) ? a.x : (j == 1) ? a.y
                                   : (j == 2) ? a.z : a.w;
                    const float wv = ysb[j] + c;
                    const float E  = exp2f(-wv * wv);
                    const float e  = (av - av * E) * mb[j];
                    l1 += e;
                    l2 += e * e;
                }
            }
        }
    }

    // ---- wave reduce (no barrier, no LDS) ----
    #pragma unroll
    for (int o = 32; o > 0; o >>= 1) {
        l1 += __shfl_down(l1, o, 64);
        l2 += __shfl_down(l2, o, 64);
    }
    if (lane == 0)
        part[b * NCHUNK + blockIdx.x] = make_float2(l1, l2);
}

__global__ __launch_bounds__(64)
void ga_final_kernel(const float2* __restrict__ part,
                     const int* __restrict__ olens,
                     float* __restrict__ out) {
    const int b  = blockIdx.x;
    const int t  = threadIdx.x;
    const int ol = olens[b];
    const int nchunks = (ol + ROWS_PER_WAVE - 1) >> 3;   // <= 256 live chunks
    float l1 = 0.0f, l2 = 0.0f;
    for (int c = t; c < nchunks; c += 64) {
        const float2 p = part[b * NCHUNK + c];
        l1 += p.x; l2 += p.y;
    }
    #pragma unroll
    for (int o = 32; o > 0; o >>= 1) {
        l1 += __shfl_down(l1, o, 64);
        l2 += __shfl_down(l2, o, 64);
    }
    if (t == 0) {
        const float d = (float)ol;
        out[b]        = l1 / d;
        out[GA_B + b] = l2 / d;
    }
}

extern "C" void kernel_launch(void* const* d_in, const int* in_sizes, int n_in,
                              void* d_out, int out_size, void* d_ws, size_t ws_size,
                              hipStream_t stream) {
    const float* att   = (const float*)d_in[0];
    const int*   ilens = (const int*)d_in[1];
    const int*   olens = (const int*)d_in[2];
    float*       out   = (float*)d_out;
    float2*      part  = (float2*)d_ws;   // 64 * 256 * 8 B = 128 KB

    dim3 grid1(NCHUNK, GA_B);
    ga_partial_kernel<<<grid1, 64, 0, stream>>>(att, ilens, olens, part);
    ga_final_kernel<<<GA_B, 64, 0, stream>>>(part, olens, out);
}